// Round 8
// baseline (124.503 us; speedup 1.0000x reference)
//
#include <hip/hip_runtime.h>
#include <hip/hip_cooperative_groups.h>
#include <math.h>

namespace cg = cooperative_groups;

#define H 1536
#define W 2048
#define SS 2000
#define SIDE 20
#define THRC 0.2f
#define ROWS 4
#define NBLK (H/ROWS)   // 384 blocks

typedef unsigned long long u64;
typedef unsigned short u16;

// ---------------- workspace layout (bytes) ----------------
constexpr size_t OFF_PART = 0;                          // float[H*8]  48 KB
constexpr size_t OFF_CNTL = (size_t)H*8*4;              // int[H]
constexpr size_t OFF_CNTR = OFF_CNTL + (size_t)H*4;     // int[H]

// ---------------- math helpers (contract off: match numpy per-op rounding) ----
struct F3 { float x, y, z; };
struct K9 { float k[9]; };

__device__ __forceinline__ F3 camAt(const float* __restrict__ depth, const K9& Ki, int y, int x) {
#pragma clang fp contract(off)
    float d = depth[y * W + x];
    float u = (float)x, v = (float)y;
    F3 p;
    p.x = (Ki.k[0] * u + Ki.k[1] * v + Ki.k[2]) * d;
    p.y = (Ki.k[3] * u + Ki.k[4] * v + Ki.k[5]) * d;
    p.z = (Ki.k[6] * u + Ki.k[7] * v + Ki.k[8]) * d;
    return p;
}

__device__ __forceinline__ F3 f3sub(F3 a, F3 b) {
#pragma clang fp contract(off)
    F3 r; r.x = a.x - b.x; r.y = a.y - b.y; r.z = a.z - b.z; return r;
}

__device__ __forceinline__ F3 crossn(F3 a, F3 b) {
#pragma clang fp contract(off)
    F3 c;
    c.x = a.y * b.z - a.z * b.y;
    c.y = a.z * b.x - a.x * b.z;
    c.z = a.x * b.y - a.y * b.x;
    float n = sqrtf(c.x * c.x + c.y * c.y + c.z * c.z) + 1e-6f;
    c.x = c.x / n; c.y = c.y / n; c.z = c.z / n;
    return c;
}

__device__ __forceinline__ F3 surfNormal(const float* __restrict__ depth, const K9& Ki, int y, int x) {
#pragma clang fp contract(off)
    F3 ctr  = camAt(depth, Ki, y, x);
    F3 x0   = camAt(depth, Ki, y, x - 1);
    F3 x1   = camAt(depth, Ki, y, x + 1);
    F3 y0   = camAt(depth, Ki, y - 1, x);
    F3 y1   = camAt(depth, Ki, y + 1, x);
    F3 x0y0 = camAt(depth, Ki, y - 1, x - 1);
    F3 x0y1 = camAt(depth, Ki, y + 1, x - 1);
    F3 x1y0 = camAt(depth, Ki, y - 1, x + 1);
    F3 x1y1 = camAt(depth, Ki, y + 1, x + 1);
    F3 n0 = crossn(f3sub(x0, ctr),   f3sub(y0, ctr));
    F3 n1 = crossn(f3sub(x1, ctr),   f3sub(y1, ctr));
    F3 n2 = crossn(f3sub(x0y0, ctr), f3sub(x0y1, ctr));
    F3 n3 = crossn(f3sub(x1y0, ctr), f3sub(x1y1, ctr));
    F3 s;
    s.x = (((n0.x + n1.x) + n2.x) + n3.x) / 4.0f;
    s.y = (((n0.y + n1.y) + n2.y) + n3.y) / 4.0f;
    s.z = (((n0.z + n1.z) + n2.z) + n3.z) / 4.0f;
    float n = sqrtf(s.x * s.x + s.y * s.y + s.z * s.z) + 1e-6f;
    s.x = s.x / n; s.y = s.y / n; s.z = s.z / n;
    return s;
}

__device__ __forceinline__ int computePos(int i, int N) {
    if (N >= SS) {
        float t = ((float)i * (float)(N - 1)) / 1999.0f;  // float32 reference parity
        return (int)floorf(t);
    } else {
        return min(i, max(N - 1, 0));
    }
}

// ---------------- the single cooperative kernel -----------------------------
__global__ __launch_bounds__(256) void k_coop(
        const float* __restrict__ depth, const int* __restrict__ mask,
        const float* __restrict__ Kinv,
        float* __restrict__ partials, int* __restrict__ cntL, int* __restrict__ cntR,
        float* __restrict__ out) {
#pragma clang fp contract(off)
    cg::grid_group grid = cg::this_grid();
    int b = blockIdx.x, t = threadIdx.x;
    int lane = t & 63, wave = t >> 6;

    __shared__ u64 sM[ROWS][32];                 // mask bits (phase1 -> phase3)
    __shared__ u64 sBL[ROWS][32], sBR[ROWS][32]; // region bitmaps (phase1 -> phase2)
    __shared__ int wcum[ROWS][33];               // union-popcount exclusive scans
    __shared__ float4 sNorm[ROWS][64];           // per-flagged-pixel normals
    __shared__ u16 sXL[ROWS][64], sXR[ROWS][64]; // inlier x lists (phase2 -> phase3)
    __shared__ int sCnt[ROWS][2];
    __shared__ int sMaskAny[ROWS];
    __shared__ float sMean[8];
    __shared__ float sW[4][8];
    __shared__ u64 wU[32], wE0[32], wE1[32];     // per-row scratch
    __shared__ unsigned char pbA[256], pbB[256]; // per-row scratch
    __shared__ int sRow[ROWS][6];
    __shared__ int sAcc[ROWS][4];
    __shared__ float sInfo[ROWS][4];
    __shared__ int sValid[ROWS];

    // ================= Phase 1: region bitmaps + normals + partials =========
    for (int r = 0; r < ROWS; ++r) {
        int y = b * ROWS + r;
        const int4* mrow = reinterpret_cast<const int4*>(mask + (size_t)y * W);
        int4 a = mrow[t * 2], b4 = mrow[t * 2 + 1];
        unsigned mbyte =
            ((unsigned)(a.x != 0))       | ((unsigned)(a.y != 0) << 1) |
            ((unsigned)(a.z != 0) << 2)  | ((unsigned)(a.w != 0) << 3) |
            ((unsigned)(b4.x != 0) << 4) | ((unsigned)(b4.y != 0) << 5) |
            ((unsigned)(b4.z != 0) << 6) | ((unsigned)(b4.w != 0) << 7);
        pbA[t] = (unsigned char)mbyte;
        __syncthreads();
        if (t < 32) sM[r][t] = reinterpret_cast<u64*>(pbA)[t];
        __syncthreads();
        if (t < 32) {
            u64 M  = sM[r][t];
            u64 Mn = (M >> 1) | ((t < 31) ? (sM[r][t + 1] << 63) : 0ull);  // m[x+1], pad 0
            wE0[t] = ~M & Mn;   // left edges  (grad == +1)
            wE1[t] = M & ~Mn;   // right edges (grad == -1)
        }
        __syncthreads();

        // 48-bit edge window covering pixels [8t-20, 8t+27]
        int base = t * 8 - SIDE;
        int wi = base >> 6;
        int ofs = base & 63;
        u64 l0 = (wi >= 0)     ? wE0[wi]     : 0ull;
        u64 l1 = (wi + 1 < 32) ? wE0[wi + 1] : 0ull;
        u64 r0 = (wi >= 0)     ? wE1[wi]     : 0ull;
        u64 r1 = (wi + 1 < 32) ? wE1[wi + 1] : 0ull;
        u64 winL = ofs ? ((l0 >> ofs) | (l1 << (64 - ofs))) : l0;
        u64 winR = ofs ? ((r0 >> ofs) | (r1 << (64 - ofs))) : r0;

        const u64 M41 = (1ull << 41) - 1;
        unsigned bL = 0, bR = 0;
#pragma unroll
        for (int j = 0; j < 8; ++j) {
            unsigned notm = (((mbyte >> j) & 1u) ^ 1u);
            unsigned dl = (((winL >> j) & M41) != 0ull) ? 1u : 0u;
            unsigned dr = (((winR >> j) & M41) != 0ull) ? 1u : 0u;
            bL |= (dl & notm) << j;
            bR |= (dr & notm) << j;
        }
        pbA[t] = (unsigned char)bL;
        pbB[t] = (unsigned char)bR;
        __syncthreads();
        if (t < 32) {
            u64 wl  = reinterpret_cast<u64*>(pbA)[t];
            u64 wr2 = reinterpret_cast<u64*>(pbB)[t];
            sBL[r][t] = wl; sBR[r][t] = wr2; wU[t] = wl | wr2;
        }
        __syncthreads();
        if (t == 0) {
            int s = 0, ma = 0;
#pragma unroll
            for (int w = 0; w < 32; ++w) {
                wcum[r][w] = s; s += __popcll(wU[w]);
                ma |= (sM[r][w] != 0ull) ? 1 : 0;
            }
            wcum[r][32] = s;
            sMaskAny[r] = ma;
        }
        __syncthreads();
        int total = wcum[r][32];
        if (total == 0) {
            if (t == 0) {
#pragma unroll
                for (int k = 0; k < 8; ++k) partials[(size_t)y * 8 + k] = 0.f;
            }
        } else if (t < 64) {
            float acc[8];
#pragma unroll
            for (int k = 0; k < 8; ++k) acc[k] = 0.f;
            if (t < min(total, 64)) {
                // union-rank t -> (word, bit)
                int lo = 0, hi = 33;
                while (lo < hi) { int mid = (lo + hi) >> 1; if (wcum[r][mid] <= t) lo = mid + 1; else hi = mid; }
                int w = lo - 1;
                int k = t - wcum[r][w];
                u64 tmp = wU[w];
                while (k--) tmp &= tmp - 1;
                int bpos = __ffsll((unsigned long long)tmp) - 1;
                int x = w * 64 + bpos;

                float nx = 0.f, ny = 0.f, nz = 0.f;
                if (x > 0 && x < W - 1 && y > 0 && y < H - 1) {
                    K9 kk;
#pragma unroll
                    for (int i = 0; i < 9; ++i) kk.k[i] = Kinv[i];
                    F3 n = surfNormal(depth, kk, y, x);
                    nx = n.x; ny = n.y; nz = n.z;
                }
                sNorm[r][t] = make_float4(nx, ny, nz, 0.f);
                bool inL = (sBL[r][w] >> bpos) & 1ull;
                bool inR = (sBR[r][w] >> bpos) & 1ull;
                if (inL) { acc[0] += nx; acc[1] += ny; acc[2] += nz; acc[3] += 1.f; }
                if (inR) { acc[4] += nx; acc[5] += ny; acc[6] += nz; acc[7] += 1.f; }
            }
#pragma unroll
            for (int k = 0; k < 8; ++k) {
                float v = acc[k];
                for (int o = 32; o > 0; o >>= 1) v += __shfl_down(v, o, 64);
                acc[k] = v;
            }
            if (t == 0) {
#pragma unroll
                for (int k = 0; k < 8; ++k) partials[(size_t)y * 8 + k] = acc[k];
            }
        }
        __syncthreads();
    }
    grid.sync();

    // ================= Phase 2: redundant mean + inlier =====================
    {
        float acc[8];
#pragma unroll
        for (int k = 0; k < 8; ++k) acc[k] = 0.f;
        for (int i = t; i < H; i += 256) {
            const float4* pr = reinterpret_cast<const float4*>(partials + (size_t)i * 8);
            float4 pa = pr[0], pb2 = pr[1];
            acc[0] += pa.x; acc[1] += pa.y; acc[2] += pa.z; acc[3] += pa.w;
            acc[4] += pb2.x; acc[5] += pb2.y; acc[6] += pb2.z; acc[7] += pb2.w;
        }
#pragma unroll
        for (int k = 0; k < 8; ++k) {
            float v = acc[k];
            for (int o = 32; o > 0; o >>= 1) v += __shfl_down(v, o, 64);
            if (lane == 0) sW[wave][k] = v;
        }
        __syncthreads();
        if (t == 0) {
            float s[8];
#pragma unroll
            for (int k = 0; k < 8; ++k) s[k] = ((sW[0][k] + sW[1][k]) + sW[2][k]) + sW[3][k];
            {
                float cnt = fmaxf(s[3], 1.f);
                float mx = s[0] / cnt, my = s[1] / cnt, mz = s[2] / cnt;
                float n = sqrtf(mx * mx + my * my + mz * mz);
                float nn = fmaxf(n, 1e-12f);
                mx = mx / nn; my = my / nn; mz = mz / nn;
                float n2 = sqrtf(mx * mx + my * my + mz * mz);
                sMean[0] = mx; sMean[1] = my; sMean[2] = mz; sMean[3] = n2;
            }
            {
                float cnt = fmaxf(s[7], 1.f);
                float mx = s[4] / cnt, my = s[5] / cnt, mz = s[6] / cnt;
                float n = sqrtf(mx * mx + my * my + mz * mz);
                float nn = fmaxf(n, 1e-12f);
                mx = mx / nn; my = my / nn; mz = mz / nn;
                float n2 = sqrtf(mx * mx + my * my + mz * mz);
                sMean[4] = mx; sMean[5] = my; sMean[6] = mz; sMean[7] = n2;
            }
        }
        __syncthreads();
    }
    for (int r = 0; r < ROWS; ++r) {
        int y = b * ROWS + r;
        int total = wcum[r][32];
        if (total > 0) {
            if (t < 64) {
                bool iL = false, iR = false;
                int x = 0;
                if (t < min(total, 64)) {
                    int lo = 0, hi = 33;
                    while (lo < hi) { int mid = (lo + hi) >> 1; if (wcum[r][mid] <= t) lo = mid + 1; else hi = mid; }
                    int w = lo - 1;
                    int k = t - wcum[r][w];
                    u64 tmp = sBL[r][w] | sBR[r][w];
                    while (k--) tmp &= tmp - 1;
                    int bpos = __ffsll((unsigned long long)tmp) - 1;
                    u64 bb = 1ull << bpos;
                    x = w * 64 + bpos;

                    float4 n = sNorm[r][t];
                    float nn = sqrtf(n.x * n.x + n.y * n.y + n.z * n.z);
                    float dn = fmaxf(nn, 1e-8f);
                    if (sBL[r][w] & bb) {
                        float dot = n.x * sMean[0] + n.y * sMean[1] + n.z * sMean[2];
                        float c = dot / (dn * fmaxf(sMean[3], 1e-8f));
                        iL = c > THRC;
                    }
                    if (sBR[r][w] & bb) {
                        float dot = n.x * sMean[4] + n.y * sMean[5] + n.z * sMean[6];
                        float c = dot / (dn * fmaxf(sMean[7], 1e-8f));
                        iR = c > THRC;
                    }
                }
                u64 balL = __ballot(iL), balR = __ballot(iR);
                u64 lm = (t == 0) ? 0ull : ((~0ull) >> (64 - t));
                if (iL) sXL[r][__popcll(balL & lm)] = (u16)x;   // ascending x
                if (iR) sXR[r][__popcll(balR & lm)] = (u16)x;
                if (t == 0) {
                    int cl = (int)__popcll(balL), cr = (int)__popcll(balR);
                    sCnt[r][0] = cl; sCnt[r][1] = cr;
                    cntL[y] = cl; cntR[y] = cr;
                }
            }
        } else {
            if (t == 0) {
                sCnt[r][0] = 0; sCnt[r][1] = 0;
                cntL[y] = 0; cntR[y] = 0;
            }
        }
    }
    __syncthreads();
    grid.sync();

    // ================= Phase 3: scan + sample + output ======================
    if (t == 0) {
#pragma unroll
        for (int r = 0; r < ROWS; ++r) { sAcc[r][0] = 0; sAcc[r][1] = 0; sAcc[r][2] = 0; sAcc[r][3] = 0; }
    }
    if (t < 64) {
        int base = t * 24;
        int sl = 0, sr = 0;
        for (int j = 0; j < 24; ++j) { sl += cntL[base + j]; sr += cntR[base + j]; }
        int iL = sl, iR = sr;
        for (int o = 1; o < 64; o <<= 1) {
            int vl = __shfl_up(iL, o, 64), vr = __shfl_up(iR, o, 64);
            if (t >= o) { iL += vl; iR += vr; }
        }
        int Nl = __shfl(iL, 63, 64), Nr = __shfl(iR, 63, 64);
        for (int r = 0; r < ROWS; ++r) {
            int y = b * ROWS + r;
            int c = y / 24;
            int cumLy = __shfl(iL - sl, c, 64);   // exclusive base of chunk c
            int cumRy = __shfl(iR - sr, c, 64);
            if (t == 0) {
                for (int j = c * 24; j < y; ++j) { cumLy += cntL[j]; cumRy += cntR[j]; }
                sRow[r][0] = cumLy; sRow[r][1] = sCnt[r][0];
                sRow[r][2] = cumRy; sRow[r][3] = sCnt[r][1];
                sRow[r][4] = Nl;    sRow[r][5] = Nr;
            }
        }
    }
    __syncthreads();
    for (int r = 0; r < ROWS; ++r) {
        int cumLy = sRow[r][0], cLy = sRow[r][1], cumRy = sRow[r][2], cRy = sRow[r][3];
        int Nl = sRow[r][4], Nr = sRow[r][5];
        int vc = (Nl > 0 && Nr > 0) ? 1 : 0;
        if (vc && (cLy | cRy)) {
            int aS = 0, aC = 0, bS = 0, bC = 0;
            for (int i = t; i < SS; i += 256) {
                int posL = computePos(i, Nl);
                int kL = posL - cumLy;
                if (kL >= 0 && kL < cLy) { aS += (int)sXL[r][kL]; aC++; }
                int posR = computePos(i, Nr);
                int kR = posR - cumRy;
                if (kR >= 0 && kR < cRy) { bS += (int)sXR[r][kR]; bC++; }
            }
            for (int o = 32; o > 0; o >>= 1) {
                aS += __shfl_down(aS, o, 64); aC += __shfl_down(aC, o, 64);
                bS += __shfl_down(bS, o, 64); bC += __shfl_down(bC, o, 64);
            }
            if (lane == 0) {
                if (aC) { atomicAdd(&sAcc[r][0], aS); atomicAdd(&sAcc[r][1], aC); }
                if (bC) { atomicAdd(&sAcc[r][2], bS); atomicAdd(&sAcc[r][3], bC); }
            }
        }
    }
    __syncthreads();
    if (t == 0) {
        for (int r = 0; r < ROWS; ++r) {
            int y = b * ROWS + r;
            int lc = sAcc[r][1], rc = sAcc[r][3];
            float lmean = (float)sAcc[r][0] / fmaxf((float)lc, 1.0f);
            float rmean = (float)sAcc[r][2] / fmaxf((float)rc, 1.0f);
            int lx = min(max((int)rintf(lmean), 0), W - 1);
            int rx = min(max((int)rintf(rmean), 0), W - 1);
            float ld = depth[(size_t)y * W + lx], rd = depth[(size_t)y * W + rx];
            int vc = (sRow[r][4] > 0 && sRow[r][5] > 0) ? 1 : 0;
            int valid = (lc > 0) && (rc > 0) && vc && (!isnan(ld)) && (!isnan(rd)) && sMaskAny[r];
            sInfo[r][0] = (float)lx; sInfo[r][1] = (float)rx; sInfo[r][2] = ld; sInfo[r][3] = rd;
            sValid[r] = valid;
        }
    }
    __syncthreads();
    for (int r = 0; r < ROWS; ++r) {
        int y = b * ROWS + r;
        u64 word = sM[r][t >> 3];
        unsigned mbyte = (unsigned)((word >> ((t & 7) * 8)) & 0xFFull);
        const float4* drow = reinterpret_cast<const float4*>(depth + (size_t)y * W);
        float4 da = drow[2 * t], db = drow[2 * t + 1];

        float slx = sInfo[r][0], srx = sInfo[r][1], sld = sInfo[r][2], srd = sInfo[r][3];
        int valid = sValid[r];
        float denom = (srx - slx) + 1e-6f;

        float d8[8] = { da.x, da.y, da.z, da.w, db.x, db.y, db.z, db.w };
        float o8[8];
        int xb = t * 8;
#pragma unroll
        for (int j = 0; j < 8; ++j) {
            float o = d8[j];
            if (valid && ((mbyte >> j) & 1u)) {
                float rr = ((float)(xb + j) - slx) / denom;
                rr = fminf(fmaxf(rr, 0.0f), 1.0f);
                o = (1.0f - rr) * sld + rr * srd;
            }
            o8[j] = o;
        }
        float4* orow = reinterpret_cast<float4*>(out + (size_t)y * W);
        orow[2 * t]     = make_float4(o8[0], o8[1], o8[2], o8[3]);
        orow[2 * t + 1] = make_float4(o8[4], o8[5], o8[6], o8[7]);
    }
}

// ---------------- launcher ---------------------------------------------------
extern "C" void kernel_launch(void* const* d_in, const int* in_sizes, int n_in,
                              void* d_out, int out_size, void* d_ws, size_t ws_size,
                              hipStream_t stream) {
    const float* depth = (const float*)d_in[0];
    const int*   mask  = (const int*)d_in[1];
    const float* Kinv  = (const float*)d_in[2];
    float* out = (float*)d_out;
    char* ws = (char*)d_ws;

    float* partials = (float*)(ws + OFF_PART);
    int* cntL = (int*)(ws + OFF_CNTL);
    int* cntR = (int*)(ws + OFF_CNTR);

    void* args[] = { (void*)&depth, (void*)&mask, (void*)&Kinv,
                     (void*)&partials, (void*)&cntL, (void*)&cntR, (void*)&out };
    hipLaunchCooperativeKernel((const void*)k_coop, dim3(NBLK), dim3(256),
                               args, 0, stream);
}

// Round 9
// 30.855 us; speedup vs baseline: 4.0350x; 4.0350x over previous
//
#include <hip/hip_runtime.h>
#include <math.h>

#define H 1536
#define W 2048
#define SS 2000
#define SIDE 20
#define THRC 0.2f

typedef unsigned long long u64;
typedef unsigned short u16;

// ---------------- workspace layout (bytes) ----------------
constexpr size_t OFF_BITL  = 0;                              // u64[H*32]   384 KB (region bitmaps)
constexpr size_t OFF_BITR  = OFF_BITL + (size_t)H*32*8;      // u64[H*32]   384 KB
constexpr size_t OFF_MBITS = OFF_BITR + (size_t)H*32*8;      // u64[H*32]   384 KB (packed mask)
constexpr size_t OFF_PART  = OFF_MBITS + (size_t)H*32*8;     // float[H*8]   48 KB
constexpr size_t OFF_CNTL  = OFF_PART + (size_t)H*8*4;       // int[H]
constexpr size_t OFF_CNTR  = OFF_CNTL + (size_t)H*4;         // int[H]
constexpr size_t OFF_NORM  = OFF_CNTR + (size_t)H*4;         // float4[H*64] 1.5 MB
constexpr size_t OFF_XL    = OFF_NORM + (size_t)H*64*16;     // u16[H*64]   196 KB (inlier x lists)
constexpr size_t OFF_XR    = OFF_XL + (size_t)H*64*2;        // u16[H*64]   196 KB

// ---------------- math helpers (contract off: match numpy per-op rounding) ----
struct F3 { float x, y, z; };
struct K9 { float k[9]; };

__device__ __forceinline__ F3 camAt(const float* __restrict__ depth, const K9& Ki, int y, int x) {
#pragma clang fp contract(off)
    float d = depth[y * W + x];
    float u = (float)x, v = (float)y;
    F3 p;
    p.x = (Ki.k[0] * u + Ki.k[1] * v + Ki.k[2]) * d;
    p.y = (Ki.k[3] * u + Ki.k[4] * v + Ki.k[5]) * d;
    p.z = (Ki.k[6] * u + Ki.k[7] * v + Ki.k[8]) * d;
    return p;
}

__device__ __forceinline__ F3 f3sub(F3 a, F3 b) {
#pragma clang fp contract(off)
    F3 r; r.x = a.x - b.x; r.y = a.y - b.y; r.z = a.z - b.z; return r;
}

__device__ __forceinline__ F3 crossn(F3 a, F3 b) {
#pragma clang fp contract(off)
    F3 c;
    c.x = a.y * b.z - a.z * b.y;
    c.y = a.z * b.x - a.x * b.z;
    c.z = a.x * b.y - a.y * b.x;
    float n = sqrtf(c.x * c.x + c.y * c.y + c.z * c.z) + 1e-6f;
    c.x = c.x / n; c.y = c.y / n; c.z = c.z / n;
    return c;
}

// ---------------- K1: region bitmaps + packed mask + 4-thread/pixel normals -
__global__ __launch_bounds__(256) void k_row_region(
        const float* __restrict__ depth, const int* __restrict__ mask,
        const float* __restrict__ Kinv,
        u64* __restrict__ bitL, u64* __restrict__ bitR, u64* __restrict__ maskBits,
        float4* __restrict__ normBuf, float* __restrict__ partials) {
#pragma clang fp contract(off)
    int y = blockIdx.x, t = threadIdx.x;
    __shared__ u64 wM[32], wE0[32], wE1[32], wU[32], sBL[32], sBR[32];
    __shared__ int wcum[33];
    __shared__ unsigned char pbA[256], pbB[256];
    __shared__ float sW[4][8];

    // load this thread's 8 mask pixels (x = 8t .. 8t+7)
    const int4* mrow = reinterpret_cast<const int4*>(mask + (size_t)y * W);
    int4 a = mrow[t * 2], b = mrow[t * 2 + 1];
    unsigned mbyte =
        ((unsigned)(a.x != 0))      | ((unsigned)(a.y != 0) << 1) |
        ((unsigned)(a.z != 0) << 2) | ((unsigned)(a.w != 0) << 3) |
        ((unsigned)(b.x != 0) << 4) | ((unsigned)(b.y != 0) << 5) |
        ((unsigned)(b.z != 0) << 6) | ((unsigned)(b.w != 0) << 7);
    pbA[t] = (unsigned char)mbyte;
    __syncthreads();
    if (t < 32) wM[t] = reinterpret_cast<u64*>(pbA)[t];
    __syncthreads();
    if (t < 32) {
        u64 M  = wM[t];
        u64 Mn = (M >> 1) | ((t < 31) ? (wM[t + 1] << 63) : 0ull);  // m[x+1], pad 0
        wE0[t] = ~M & Mn;   // left edges  (grad == +1)
        wE1[t] = M & ~Mn;   // right edges (grad == -1)
        maskBits[(size_t)y * 32 + t] = M;
    }
    __syncthreads();

    // 48-bit edge window covering pixels [8t-20, 8t+27]
    int base = t * 8 - SIDE;
    int wi = base >> 6;
    int ofs = base & 63;
    u64 l0 = (wi >= 0)     ? wE0[wi]     : 0ull;
    u64 l1 = (wi + 1 < 32) ? wE0[wi + 1] : 0ull;
    u64 r0 = (wi >= 0)     ? wE1[wi]     : 0ull;
    u64 r1 = (wi + 1 < 32) ? wE1[wi + 1] : 0ull;
    u64 winL = ofs ? ((l0 >> ofs) | (l1 << (64 - ofs))) : l0;
    u64 winR = ofs ? ((r0 >> ofs) | (r1 << (64 - ofs))) : r0;

    const u64 M41 = (1ull << 41) - 1;
    unsigned bL = 0, bR = 0;
#pragma unroll
    for (int j = 0; j < 8; ++j) {
        unsigned notm = (((mbyte >> j) & 1u) ^ 1u);
        unsigned dl = (((winL >> j) & M41) != 0ull) ? 1u : 0u;
        unsigned dr = (((winR >> j) & M41) != 0ull) ? 1u : 0u;
        bL |= (dl & notm) << j;
        bR |= (dr & notm) << j;
    }

    // pack region bitmaps to global + union words
    pbA[t] = (unsigned char)bL;
    pbB[t] = (unsigned char)bR;
    __syncthreads();
    if (t < 32) {
        u64 wl  = reinterpret_cast<u64*>(pbA)[t];
        u64 wr2 = reinterpret_cast<u64*>(pbB)[t];
        bitL[(size_t)y * 32 + t] = wl;
        bitR[(size_t)y * 32 + t] = wr2;
        sBL[t] = wl; sBR[t] = wr2; wU[t] = wl | wr2;
    }
    __syncthreads();
    if (t == 0) {
        int s = 0;
#pragma unroll
        for (int w = 0; w < 32; ++w) { wcum[w] = s; s += __popcll(wU[w]); }
        wcum[32] = s;
    }
    __syncthreads();
    int total = wcum[32];
    if (total == 0) {
        if (t == 0) {
#pragma unroll
            for (int k = 0; k < 8; ++k) partials[(size_t)y * 8 + k] = 0.f;
        }
        return;
    }

    // ---- 4 threads per flagged pixel: group g = t>>2, member j = t&3 ----
    int g = t >> 2, j = t & 3;
    int lane = t & 63, wave = t >> 6;
    float acc[8];
#pragma unroll
    for (int k = 0; k < 8; ++k) acc[k] = 0.f;

    if (g < min(total, 64)) {
        // union-rank g -> (word, bit)
        int lo = 0, hi = 33;
        while (lo < hi) { int mid = (lo + hi) >> 1; if (wcum[mid] <= g) lo = mid + 1; else hi = mid; }
        int w = lo - 1;
        int k = g - wcum[w];
        u64 tmp = wU[w];
        while (k--) tmp &= tmp - 1;
        int bpos = __ffsll((unsigned long long)tmp) - 1;
        int x = w * 64 + bpos;
        bool inL = (sBL[w] >> bpos) & 1ull;
        bool inR = (sBR[w] >> bpos) & 1ull;

        F3 nj; nj.x = 0.f; nj.y = 0.f; nj.z = 0.f;
        if (x > 0 && x < W - 1 && y > 0 && y < H - 1) {
            K9 kk;
#pragma unroll
            for (int i = 0; i < 9; ++i) kk.k[i] = Kinv[i];
            F3 ctr = camAt(depth, kk, y, x);
            F3 pa, pb;
            if (j == 0)      { pa = camAt(depth, kk, y, x - 1);     pb = camAt(depth, kk, y - 1, x); }
            else if (j == 1) { pa = camAt(depth, kk, y, x + 1);     pb = camAt(depth, kk, y + 1, x); }
            else if (j == 2) { pa = camAt(depth, kk, y - 1, x - 1); pb = camAt(depth, kk, y + 1, x - 1); }
            else             { pa = camAt(depth, kk, y - 1, x + 1); pb = camAt(depth, kk, y + 1, x + 1); }
            nj = crossn(f3sub(pa, ctr), f3sub(pb, ctr));
        }
        // gather n1,n2,n3 to member 0 of the group (same wave: lanes baseLane+1..3)
        int baseLane = lane & ~3;
        float n1x = __shfl(nj.x, baseLane + 1, 64), n1y = __shfl(nj.y, baseLane + 1, 64), n1z = __shfl(nj.z, baseLane + 1, 64);
        float n2x = __shfl(nj.x, baseLane + 2, 64), n2y = __shfl(nj.y, baseLane + 2, 64), n2z = __shfl(nj.z, baseLane + 2, 64);
        float n3x = __shfl(nj.x, baseLane + 3, 64), n3y = __shfl(nj.y, baseLane + 3, 64), n3z = __shfl(nj.z, baseLane + 3, 64);
        if (j == 0) {
            // exact reference order: (((n0+n1)+n2)+n3)/4, then normalize by (norm+1e-6)
            float sx = (((nj.x + n1x) + n2x) + n3x) / 4.0f;
            float sy = (((nj.y + n1y) + n2y) + n3y) / 4.0f;
            float sz = (((nj.z + n1z) + n2z) + n3z) / 4.0f;
            float n = sqrtf(sx * sx + sy * sy + sz * sz) + 1e-6f;
            sx = sx / n; sy = sy / n; sz = sz / n;
            normBuf[(size_t)y * 64 + g] = make_float4(sx, sy, sz, 0.f);
            if (inL) { acc[0] += sx; acc[1] += sy; acc[2] += sz; acc[3] += 1.f; }
            if (inR) { acc[4] += sx; acc[5] += sy; acc[6] += sz; acc[7] += 1.f; }
        }
    }
    // block-wide fixed-tree reduction of acc[8]
#pragma unroll
    for (int k = 0; k < 8; ++k) {
        float v = acc[k];
        for (int o = 32; o > 0; o >>= 1) v += __shfl_down(v, o, 64);
        if (lane == 0) sW[wave][k] = v;
    }
    __syncthreads();
    if (t == 0) {
#pragma unroll
        for (int k = 0; k < 8; ++k)
            partials[(size_t)y * 8 + k] = ((sW[0][k] + sW[1][k]) + sW[2][k]) + sW[3][k];
    }
}

// ---------------- K2: redundant mean + 1-wave inlier -> compacted x lists ---
__global__ __launch_bounds__(256) void k_mean_inlier(
        const float* __restrict__ partials,
        const u64* __restrict__ bitL, const u64* __restrict__ bitR,
        const float4* __restrict__ normBuf,
        u16* __restrict__ xListL, u16* __restrict__ xListR,
        int* __restrict__ cntL, int* __restrict__ cntR) {
#pragma clang fp contract(off)
    int y = blockIdx.x, t = threadIdx.x;
    __shared__ u64 sUL[32], sUR[32];
    __shared__ int sExcl[33];
    __shared__ float sW[4][8];
    __shared__ float sMean[8];

    // wave 0: load row bitmaps + per-word exclusive ranks (before any barrier)
    u64 ul = 0, ur = 0;
    int total = 0;
    if (t < 64) {
        if (t < 32) { ul = bitL[(size_t)y * 32 + t]; ur = bitR[(size_t)y * 32 + t]; sUL[t] = ul; sUR[t] = ur; }
        u64 uu = ul | ur;
        int pc = __popcll(uu);
        int pref = pc;
        for (int o = 1; o < 64; o <<= 1) {
            int v = __shfl_up(pref, o, 64);
            if (t >= o) pref += v;
        }
        if (t < 32) sExcl[t] = pref - pc;
        if (t == 31) sExcl[32] = pref;
        total = __shfl(pref, 63, 64);
    }
    int any = __syncthreads_or((t < 32) && ((ul | ur) != 0ull));
    if (!any) {
        if (t == 0) { cntL[y] = 0; cntR[y] = 0; }
        return;
    }

    // ---- phase A: redundant global mean (structure identical to old k_mean) ----
    float acc[8];
#pragma unroll
    for (int k = 0; k < 8; ++k) acc[k] = 0.f;
    for (int i = t; i < H; i += 256) {
        const float4* pr = reinterpret_cast<const float4*>(partials + (size_t)i * 8);
        float4 pa = pr[0], pb = pr[1];
        acc[0] += pa.x; acc[1] += pa.y; acc[2] += pa.z; acc[3] += pa.w;
        acc[4] += pb.x; acc[5] += pb.y; acc[6] += pb.z; acc[7] += pb.w;
    }
    int wave = t >> 6, lane = t & 63;
#pragma unroll
    for (int k = 0; k < 8; ++k) {
        float v = acc[k];
        for (int o = 32; o > 0; o >>= 1) v += __shfl_down(v, o, 64);
        if (lane == 0) sW[wave][k] = v;
    }
    __syncthreads();
    if (t == 0) {
        float s[8];
#pragma unroll
        for (int k = 0; k < 8; ++k) s[k] = ((sW[0][k] + sW[1][k]) + sW[2][k]) + sW[3][k];
        {
            float cnt = fmaxf(s[3], 1.f);
            float mx = s[0] / cnt, my = s[1] / cnt, mz = s[2] / cnt;
            float n = sqrtf(mx * mx + my * my + mz * mz);
            float nn = fmaxf(n, 1e-12f);
            mx = mx / nn; my = my / nn; mz = mz / nn;
            float n2 = sqrtf(mx * mx + my * my + mz * mz);
            sMean[0] = mx; sMean[1] = my; sMean[2] = mz; sMean[3] = n2;
        }
        {
            float cnt = fmaxf(s[7], 1.f);
            float mx = s[4] / cnt, my = s[5] / cnt, mz = s[6] / cnt;
            float n = sqrtf(mx * mx + my * my + mz * mz);
            float nn = fmaxf(n, 1e-12f);
            mx = mx / nn; my = my / nn; mz = mz / nn;
            float n2 = sqrtf(mx * mx + my * my + mz * mz);
            sMean[4] = mx; sMean[5] = my; sMean[6] = mz; sMean[7] = n2;
        }
    }
    __syncthreads();
    if (t >= 64) return;

    // ---- phase B: wave-0 inlier test ----
    bool iL = false, iR = false;
    int x = 0;
    if (t < min(total, 64)) {
        int lo = 0, hi = 33;
        while (lo < hi) { int mid = (lo + hi) >> 1; if (sExcl[mid] <= t) lo = mid + 1; else hi = mid; }
        int w = lo - 1;
        int k = t - sExcl[w];
        u64 tmp = sUL[w] | sUR[w];
        while (k--) tmp &= tmp - 1;
        int bpos = __ffsll((unsigned long long)tmp) - 1;
        u64 bb = 1ull << bpos;
        x = w * 64 + bpos;

        float4 n = normBuf[(size_t)y * 64 + t];   // coalesced: slot == union rank == t
        float nn = sqrtf(n.x * n.x + n.y * n.y + n.z * n.z);
        float dn = fmaxf(nn, 1e-8f);
        if (sUL[w] & bb) {
            float dot = n.x * sMean[0] + n.y * sMean[1] + n.z * sMean[2];
            float c = dot / (dn * fmaxf(sMean[3], 1e-8f));
            iL = c > THRC;
        }
        if (sUR[w] & bb) {
            float dot = n.x * sMean[4] + n.y * sMean[5] + n.z * sMean[6];
            float c = dot / (dn * fmaxf(sMean[7], 1e-8f));
            iR = c > THRC;
        }
    }
    u64 balL = __ballot(iL), balR = __ballot(iR);
    u64 lm = (t == 0) ? 0ull : ((~0ull) >> (64 - t));
    if (iL) xListL[(size_t)y * 64 + __popcll(balL & lm)] = (u16)x;  // ascending x
    if (iR) xListR[(size_t)y * 64 + __popcll(balR & lm)] = (u16)x;
    if (t == 0) { cntL[y] = (int)__popcll(balL); cntR[y] = (int)__popcll(balR); }
}

// ---------------- K3: parallel redundant scan + sampling + output -----------
__device__ __forceinline__ int computePos(int i, int N) {
    if (N >= SS) {
        float t = ((float)i * (float)(N - 1)) / 1999.0f;  // float32 reference parity
        return (int)floorf(t);
    } else {
        return min(i, max(N - 1, 0));
    }
}

__global__ __launch_bounds__(256) void k_out(
        const float* __restrict__ depth, const u64* __restrict__ maskBits,
        const int* __restrict__ cntL, const int* __restrict__ cntR,
        const u16* __restrict__ xListL, const u16* __restrict__ xListR,
        float* __restrict__ out) {
#pragma clang fp contract(off)
    int y = blockIdx.x, t = threadIdx.x;
    __shared__ int sAcc[4];            // accLs, accLc, accRs, accRc
    __shared__ int sRow[4];            // cumLy, cLy, cumRy, cRy
    __shared__ int sTw[4][2];
    __shared__ float sInfo[4];         // slx, srx, sld, srd
    __shared__ int sValid;

    if (t == 0) {
        sAcc[0] = 0; sAcc[1] = 0; sAcc[2] = 0; sAcc[3] = 0;
        sRow[1] = cntL[y]; sRow[3] = cntR[y];
    }

    u64 word = maskBits[(size_t)y * 32 + (t >> 3)];   // 8 threads share a word (broadcast)
    unsigned mbyte = (unsigned)((word >> ((t & 7) * 8)) & 0xFFull);
    const float4* drow = reinterpret_cast<const float4*>(depth + (size_t)y * W);
    float4 da = drow[2 * t], db = drow[2 * t + 1];
    int rowAny = __syncthreads_or(word != 0ull);      // also fences sAcc/sRow init

    // parallel redundant scan: thread t covers rows [6t, 6t+6)
    int lane = t & 63, wave = t >> 6;
    int base6 = t * 6;
    int cl[6], cr[6];
    int sl = 0, sr = 0;
#pragma unroll
    for (int jj = 0; jj < 6; ++jj) {
        cl[jj] = cntL[base6 + jj]; cr[jj] = cntR[base6 + jj];
        sl += cl[jj]; sr += cr[jj];
    }
    int il = sl, ir = sr;
    for (int o = 1; o < 64; o <<= 1) {
        int vl = __shfl_up(il, o, 64), vr = __shfl_up(ir, o, 64);
        if (lane >= o) { il += vl; ir += vr; }
    }
    if (lane == 63) { sTw[wave][0] = il; sTw[wave][1] = ir; }
    __syncthreads();
    int Nl = ((sTw[0][0] + sTw[1][0]) + sTw[2][0]) + sTw[3][0];
    int Nr = ((sTw[0][1] + sTw[1][1]) + sTw[2][1]) + sTw[3][1];
    if (t == y / 6) {
        int wbl = 0, wbr = 0;
        for (int w2 = 0; w2 < wave; ++w2) { wbl += sTw[w2][0]; wbr += sTw[w2][1]; }
        int cumLy = wbl + il - sl;     // exclusive base of this 6-row chunk
        int cumRy = wbr + ir - sr;
        int rem = y - base6;
#pragma unroll
        for (int jj = 0; jj < 6; ++jj) {
            if (jj < rem) { cumLy += cl[jj]; cumRy += cr[jj]; }
        }
        sRow[0] = cumLy; sRow[2] = cumRy;
    }
    __syncthreads();
    int cumLy = sRow[0], cLy = sRow[1], cumRy = sRow[2], cRy = sRow[3];
    int vc = (Nl > 0 && Nr > 0) ? 1 : 0;

    // all threads: enumerate the 2000 samples, keep those landing in this row
    if (vc && (cLy | cRy)) {
        int aS = 0, aC = 0, bS = 0, bC = 0;
        for (int i = t; i < SS; i += 256) {
            int posL = computePos(i, Nl);
            int kL = posL - cumLy;
            if (kL >= 0 && kL < cLy) { aS += (int)xListL[(size_t)y * 64 + kL]; aC++; }
            int posR = computePos(i, Nr);
            int kR = posR - cumRy;
            if (kR >= 0 && kR < cRy) { bS += (int)xListR[(size_t)y * 64 + kR]; bC++; }
        }
        for (int o = 32; o > 0; o >>= 1) {
            aS += __shfl_down(aS, o, 64); aC += __shfl_down(aC, o, 64);
            bS += __shfl_down(bS, o, 64); bC += __shfl_down(bC, o, 64);
        }
        if (lane == 0) {
            if (aC) { atomicAdd(&sAcc[0], aS); atomicAdd(&sAcc[1], aC); }
            if (bC) { atomicAdd(&sAcc[2], bS); atomicAdd(&sAcc[3], bC); }
        }
    }
    __syncthreads();

    if (t == 0) {
        int lc = sAcc[1], rc = sAcc[3];
        float lmean = (float)sAcc[0] / fmaxf((float)lc, 1.0f);
        float rmean = (float)sAcc[2] / fmaxf((float)rc, 1.0f);
        int lx = min(max((int)rintf(lmean), 0), W - 1);
        int rx = min(max((int)rintf(rmean), 0), W - 1);
        float ld = depth[(size_t)y * W + lx], rd = depth[(size_t)y * W + rx];
        int valid = (lc > 0) && (rc > 0) && vc && (!isnan(ld)) && (!isnan(rd)) && rowAny;
        sInfo[0] = (float)lx; sInfo[1] = (float)rx; sInfo[2] = ld; sInfo[3] = rd;
        sValid = valid;
    }
    __syncthreads();

    float slx = sInfo[0], srx = sInfo[1], sld = sInfo[2], srd = sInfo[3];
    int valid = sValid;
    float denom = (srx - slx) + 1e-6f;

    float d8[8] = { da.x, da.y, da.z, da.w, db.x, db.y, db.z, db.w };
    float o8[8];
    int xb = t * 8;
#pragma unroll
    for (int j = 0; j < 8; ++j) {
        float o = d8[j];
        if (valid && ((mbyte >> j) & 1u)) {
            float r = ((float)(xb + j) - slx) / denom;
            r = fminf(fmaxf(r, 0.0f), 1.0f);
            o = (1.0f - r) * sld + r * srd;
        }
        o8[j] = o;
    }
    float4* orow = reinterpret_cast<float4*>(out + (size_t)y * W);
    orow[2 * t]     = make_float4(o8[0], o8[1], o8[2], o8[3]);
    orow[2 * t + 1] = make_float4(o8[4], o8[5], o8[6], o8[7]);
}

// ---------------- launcher ---------------------------------------------------
extern "C" void kernel_launch(void* const* d_in, const int* in_sizes, int n_in,
                              void* d_out, int out_size, void* d_ws, size_t ws_size,
                              hipStream_t stream) {
    const float* depth = (const float*)d_in[0];
    const int*   mask  = (const int*)d_in[1];
    const float* Kinv  = (const float*)d_in[2];
    float* out = (float*)d_out;
    char* ws = (char*)d_ws;

    u64* bitL = (u64*)(ws + OFF_BITL);
    u64* bitR = (u64*)(ws + OFF_BITR);
    u64* maskBits = (u64*)(ws + OFF_MBITS);
    float* partials = (float*)(ws + OFF_PART);
    int* cntL = (int*)(ws + OFF_CNTL);
    int* cntR = (int*)(ws + OFF_CNTR);
    float4* normBuf = (float4*)(ws + OFF_NORM);
    u16* xListL = (u16*)(ws + OFF_XL);
    u16* xListR = (u16*)(ws + OFF_XR);

    k_row_region<<<H, 256, 0, stream>>>(depth, mask, Kinv, bitL, bitR, maskBits, normBuf, partials);
    k_mean_inlier<<<H, 256, 0, stream>>>(partials, bitL, bitR, normBuf, xListL, xListR, cntL, cntR);
    k_out<<<H, 256, 0, stream>>>(depth, maskBits, cntL, cntR, xListL, xListR, out);
}

// Round 10
// 29.359 us; speedup vs baseline: 4.2407x; 1.0510x over previous
//
#include <hip/hip_runtime.h>
#include <math.h>

#define H 1536
#define W 2048
#define SS 2000
#define SIDE 20
#define THRC 0.2f

typedef unsigned long long u64;
typedef unsigned short u16;

// ---------------- workspace layout (bytes) ----------------
constexpr size_t OFF_BITL  = 0;                              // u64[H*32]   384 KB (region bitmaps)
constexpr size_t OFF_BITR  = OFF_BITL + (size_t)H*32*8;      // u64[H*32]   384 KB
constexpr size_t OFF_MBITS = OFF_BITR + (size_t)H*32*8;      // u64[H*32]   384 KB (packed mask)
constexpr size_t OFF_PART  = OFF_MBITS + (size_t)H*32*8;     // float[H*8]   48 KB
constexpr size_t OFF_CNTL  = OFF_PART + (size_t)H*8*4;       // int[H]
constexpr size_t OFF_CNTR  = OFF_CNTL + (size_t)H*4;         // int[H]
constexpr size_t OFF_NORM  = OFF_CNTR + (size_t)H*4;         // float4[H*64] 1.5 MB
constexpr size_t OFF_XL    = OFF_NORM + (size_t)H*64*16;     // u16[H*64]   196 KB (inlier x lists)
constexpr size_t OFF_XR    = OFF_XL + (size_t)H*64*2;        // u16[H*64]   196 KB

// ---------------- math helpers (contract off: match numpy per-op rounding) ----
struct F3 { float x, y, z; };
struct K9 { float k[9]; };

__device__ __forceinline__ F3 camAt(const float* __restrict__ depth, const K9& Ki, int y, int x) {
#pragma clang fp contract(off)
    float d = depth[y * W + x];
    float u = (float)x, v = (float)y;
    F3 p;
    p.x = (Ki.k[0] * u + Ki.k[1] * v + Ki.k[2]) * d;
    p.y = (Ki.k[3] * u + Ki.k[4] * v + Ki.k[5]) * d;
    p.z = (Ki.k[6] * u + Ki.k[7] * v + Ki.k[8]) * d;
    return p;
}

__device__ __forceinline__ F3 f3sub(F3 a, F3 b) {
#pragma clang fp contract(off)
    F3 r; r.x = a.x - b.x; r.y = a.y - b.y; r.z = a.z - b.z; return r;
}

__device__ __forceinline__ F3 crossn(F3 a, F3 b) {
#pragma clang fp contract(off)
    F3 c;
    c.x = a.y * b.z - a.z * b.y;
    c.y = a.z * b.x - a.x * b.z;
    c.z = a.x * b.y - a.y * b.x;
    float n = sqrtf(c.x * c.x + c.y * c.y + c.z * c.z) + 1e-6f;
    c.x = c.x / n; c.y = c.y / n; c.z = c.z / n;
    return c;
}

__device__ __forceinline__ F3 surfNormal(const float* __restrict__ depth, const K9& Ki, int y, int x) {
#pragma clang fp contract(off)
    F3 ctr  = camAt(depth, Ki, y, x);
    F3 x0   = camAt(depth, Ki, y, x - 1);
    F3 x1   = camAt(depth, Ki, y, x + 1);
    F3 y0   = camAt(depth, Ki, y - 1, x);
    F3 y1   = camAt(depth, Ki, y + 1, x);
    F3 x0y0 = camAt(depth, Ki, y - 1, x - 1);
    F3 x0y1 = camAt(depth, Ki, y + 1, x - 1);
    F3 x1y0 = camAt(depth, Ki, y - 1, x + 1);
    F3 x1y1 = camAt(depth, Ki, y + 1, x + 1);
    F3 n0 = crossn(f3sub(x0, ctr),   f3sub(y0, ctr));
    F3 n1 = crossn(f3sub(x1, ctr),   f3sub(y1, ctr));
    F3 n2 = crossn(f3sub(x0y0, ctr), f3sub(x0y1, ctr));
    F3 n3 = crossn(f3sub(x1y0, ctr), f3sub(x1y1, ctr));
    F3 s;
    s.x = (((n0.x + n1.x) + n2.x) + n3.x) / 4.0f;
    s.y = (((n0.y + n1.y) + n2.y) + n3.y) / 4.0f;
    s.z = (((n0.z + n1.z) + n2.z) + n3.z) / 4.0f;
    float n = sqrtf(s.x * s.x + s.y * s.y + s.z * s.z) + 1e-6f;
    s.x = s.x / n; s.y = s.y / n; s.z = s.z / n;
    return s;
}

// ---------------- K1: region bitmaps + packed mask + lane-parallel normals --
__global__ __launch_bounds__(256) void k_row_region(
        const float* __restrict__ depth, const int* __restrict__ mask,
        const float* __restrict__ Kinv,
        u64* __restrict__ bitL, u64* __restrict__ bitR, u64* __restrict__ maskBits,
        float4* __restrict__ normBuf, float* __restrict__ partials) {
    int y = blockIdx.x, t = threadIdx.x;
    __shared__ u64 wM[32], wE0[32], wE1[32], wU[32], sBL[32], sBR[32];
    __shared__ int wcum[33];
    __shared__ unsigned char pbA[256], pbB[256];

    // load this thread's 8 mask pixels (x = 8t .. 8t+7)
    const int4* mrow = reinterpret_cast<const int4*>(mask + (size_t)y * W);
    int4 a = mrow[t * 2], b = mrow[t * 2 + 1];
    unsigned mbyte =
        ((unsigned)(a.x != 0))      | ((unsigned)(a.y != 0) << 1) |
        ((unsigned)(a.z != 0) << 2) | ((unsigned)(a.w != 0) << 3) |
        ((unsigned)(b.x != 0) << 4) | ((unsigned)(b.y != 0) << 5) |
        ((unsigned)(b.z != 0) << 6) | ((unsigned)(b.w != 0) << 7);
    pbA[t] = (unsigned char)mbyte;
    __syncthreads();
    if (t < 32) wM[t] = reinterpret_cast<u64*>(pbA)[t];
    __syncthreads();
    if (t < 32) {
        u64 M  = wM[t];
        u64 Mn = (M >> 1) | ((t < 31) ? (wM[t + 1] << 63) : 0ull);  // m[x+1], pad 0
        wE0[t] = ~M & Mn;   // left edges  (grad == +1)
        wE1[t] = M & ~Mn;   // right edges (grad == -1)
        maskBits[(size_t)y * 32 + t] = M;
    }
    __syncthreads();

    // 48-bit edge window covering pixels [8t-20, 8t+27]
    int base = t * 8 - SIDE;
    int wi = base >> 6;
    int ofs = base & 63;
    u64 l0 = (wi >= 0)     ? wE0[wi]     : 0ull;
    u64 l1 = (wi + 1 < 32) ? wE0[wi + 1] : 0ull;
    u64 r0 = (wi >= 0)     ? wE1[wi]     : 0ull;
    u64 r1 = (wi + 1 < 32) ? wE1[wi + 1] : 0ull;
    u64 winL = ofs ? ((l0 >> ofs) | (l1 << (64 - ofs))) : l0;
    u64 winR = ofs ? ((r0 >> ofs) | (r1 << (64 - ofs))) : r0;

    const u64 M41 = (1ull << 41) - 1;
    unsigned bL = 0, bR = 0;
#pragma unroll
    for (int j = 0; j < 8; ++j) {
        unsigned notm = (((mbyte >> j) & 1u) ^ 1u);
        unsigned dl = (((winL >> j) & M41) != 0ull) ? 1u : 0u;
        unsigned dr = (((winR >> j) & M41) != 0ull) ? 1u : 0u;
        bL |= (dl & notm) << j;
        bR |= (dr & notm) << j;
    }
    unsigned bAny = bL | bR;

    // pack region bitmaps to global + union words
    pbA[t] = (unsigned char)bL;
    pbB[t] = (unsigned char)bR;
    __syncthreads();
    if (t < 32) {
        u64 wl  = reinterpret_cast<u64*>(pbA)[t];
        u64 wr2 = reinterpret_cast<u64*>(pbB)[t];
        bitL[(size_t)y * 32 + t] = wl;
        bitR[(size_t)y * 32 + t] = wr2;
        sBL[t] = wl; sBR[t] = wr2; wU[t] = wl | wr2;
    }
    __syncthreads();
    if (t == 0) {
        int s = 0;
#pragma unroll
        for (int w = 0; w < 32; ++w) { wcum[w] = s; s += __popcll(wU[w]); }
        wcum[32] = s;
    }
    __syncthreads();
    int total = wcum[32];
    if (total == 0) {
        if (t == 0) {
#pragma unroll
            for (int k = 0; k < 8; ++k) partials[(size_t)y * 8 + k] = 0.f;
        }
        return;
    }
    if (t >= 64) return;  // wave 0 handles all flagged pixels (one lane each)

    float acc[8];
#pragma unroll
    for (int k = 0; k < 8; ++k) acc[k] = 0.f;

    if (t < min(total, 64)) {
        // union-rank t -> (word, bit): largest w with wcum[w] <= t
        int lo = 0, hi = 33;
        while (lo < hi) { int mid = (lo + hi) >> 1; if (wcum[mid] <= t) lo = mid + 1; else hi = mid; }
        int w = lo - 1;
        int k = t - wcum[w];
        u64 tmp = wU[w];
        while (k--) tmp &= tmp - 1;
        int bpos = __ffsll((unsigned long long)tmp) - 1;
        int x = w * 64 + bpos;

        float nx = 0.f, ny = 0.f, nz = 0.f;
        if (x > 0 && x < W - 1 && y > 0 && y < H - 1) {
            K9 kk;
#pragma unroll
            for (int i = 0; i < 9; ++i) kk.k[i] = Kinv[i];
            F3 n = surfNormal(depth, kk, y, x);
            nx = n.x; ny = n.y; nz = n.z;
        }
        normBuf[(size_t)y * 64 + t] = make_float4(nx, ny, nz, 0.f);  // coalesced
        bool inL = (sBL[w] >> bpos) & 1ull;
        bool inR = (sBR[w] >> bpos) & 1ull;
        if (inL) { acc[0] += nx; acc[1] += ny; acc[2] += nz; acc[3] += 1.f; }
        if (inR) { acc[4] += nx; acc[5] += ny; acc[6] += nz; acc[7] += 1.f; }
    }
    // single-wave shfl reduction (deterministic fixed tree)
#pragma unroll
    for (int k = 0; k < 8; ++k) {
        float v = acc[k];
        for (int o = 32; o > 0; o >>= 1) v += __shfl_down(v, o, 64);
        acc[k] = v;
    }
    if (t == 0) {
#pragma unroll
        for (int k = 0; k < 8; ++k) partials[(size_t)y * 8 + k] = acc[k];
    }
}

// ---------------- K2: redundant mean + 1-wave inlier -> compacted x lists ---
__global__ __launch_bounds__(256) void k_mean_inlier(
        const float* __restrict__ partials,
        const u64* __restrict__ bitL, const u64* __restrict__ bitR,
        const float4* __restrict__ normBuf,
        u16* __restrict__ xListL, u16* __restrict__ xListR,
        int* __restrict__ cntL, int* __restrict__ cntR) {
#pragma clang fp contract(off)
    int y = blockIdx.x, t = threadIdx.x;
    __shared__ u64 sUL[32], sUR[32];
    __shared__ int sExcl[33];
    __shared__ float sW[4][8];
    __shared__ float sMean[8];

    // wave 0: load row bitmaps + per-word exclusive ranks (before any barrier)
    u64 ul = 0, ur = 0;
    int total = 0;
    if (t < 64) {
        if (t < 32) { ul = bitL[(size_t)y * 32 + t]; ur = bitR[(size_t)y * 32 + t]; sUL[t] = ul; sUR[t] = ur; }
        u64 uu = ul | ur;
        int pc = __popcll(uu);
        int pref = pc;
        for (int o = 1; o < 64; o <<= 1) {
            int v = __shfl_up(pref, o, 64);
            if (t >= o) pref += v;
        }
        if (t < 32) sExcl[t] = pref - pc;
        if (t == 31) sExcl[32] = pref;
        total = __shfl(pref, 63, 64);
    }
    int any = __syncthreads_or((t < 32) && ((ul | ur) != 0ull));
    if (!any) {
        if (t == 0) { cntL[y] = 0; cntR[y] = 0; }
        return;
    }

    // ---- phase A: redundant global mean (structure identical to old k_mean) ----
    float acc[8];
#pragma unroll
    for (int k = 0; k < 8; ++k) acc[k] = 0.f;
    for (int i = t; i < H; i += 256) {
        const float4* pr = reinterpret_cast<const float4*>(partials + (size_t)i * 8);
        float4 pa = pr[0], pb = pr[1];
        acc[0] += pa.x; acc[1] += pa.y; acc[2] += pa.z; acc[3] += pa.w;
        acc[4] += pb.x; acc[5] += pb.y; acc[6] += pb.z; acc[7] += pb.w;
    }
    int wave = t >> 6, lane = t & 63;
#pragma unroll
    for (int k = 0; k < 8; ++k) {
        float v = acc[k];
        for (int o = 32; o > 0; o >>= 1) v += __shfl_down(v, o, 64);
        if (lane == 0) sW[wave][k] = v;
    }
    __syncthreads();
    if (t == 0) {
        float s[8];
#pragma unroll
        for (int k = 0; k < 8; ++k) s[k] = ((sW[0][k] + sW[1][k]) + sW[2][k]) + sW[3][k];
        {
            float cnt = fmaxf(s[3], 1.f);
            float mx = s[0] / cnt, my = s[1] / cnt, mz = s[2] / cnt;
            float n = sqrtf(mx * mx + my * my + mz * mz);
            float nn = fmaxf(n, 1e-12f);
            mx = mx / nn; my = my / nn; mz = mz / nn;
            float n2 = sqrtf(mx * mx + my * my + mz * mz);
            sMean[0] = mx; sMean[1] = my; sMean[2] = mz; sMean[3] = n2;
        }
        {
            float cnt = fmaxf(s[7], 1.f);
            float mx = s[4] / cnt, my = s[5] / cnt, mz = s[6] / cnt;
            float n = sqrtf(mx * mx + my * my + mz * mz);
            float nn = fmaxf(n, 1e-12f);
            mx = mx / nn; my = my / nn; mz = mz / nn;
            float n2 = sqrtf(mx * mx + my * my + mz * mz);
            sMean[4] = mx; sMean[5] = my; sMean[6] = mz; sMean[7] = n2;
        }
    }
    __syncthreads();
    if (t >= 64) return;

    // ---- phase B: wave-0 inlier test (means from LDS) ----
    bool iL = false, iR = false;
    int x = 0;
    if (t < min(total, 64)) {
        int lo = 0, hi = 33;
        while (lo < hi) { int mid = (lo + hi) >> 1; if (sExcl[mid] <= t) lo = mid + 1; else hi = mid; }
        int w = lo - 1;
        int k = t - sExcl[w];
        u64 tmp = sUL[w] | sUR[w];
        while (k--) tmp &= tmp - 1;
        int bpos = __ffsll((unsigned long long)tmp) - 1;
        u64 bb = 1ull << bpos;
        x = w * 64 + bpos;

        float4 n = normBuf[(size_t)y * 64 + t];   // coalesced: slot == union rank == t
        float nn = sqrtf(n.x * n.x + n.y * n.y + n.z * n.z);
        float dn = fmaxf(nn, 1e-8f);
        if (sUL[w] & bb) {
            float dot = n.x * sMean[0] + n.y * sMean[1] + n.z * sMean[2];
            float c = dot / (dn * fmaxf(sMean[3], 1e-8f));
            iL = c > THRC;
        }
        if (sUR[w] & bb) {
            float dot = n.x * sMean[4] + n.y * sMean[5] + n.z * sMean[6];
            float c = dot / (dn * fmaxf(sMean[7], 1e-8f));
            iR = c > THRC;
        }
    }
    u64 balL = __ballot(iL), balR = __ballot(iR);
    u64 lm = (t == 0) ? 0ull : ((~0ull) >> (64 - t));
    if (iL) xListL[(size_t)y * 64 + __popcll(balL & lm)] = (u16)x;  // ascending x
    if (iR) xListR[(size_t)y * 64 + __popcll(balR & lm)] = (u16)x;
    if (t == 0) { cntL[y] = (int)__popcll(balL); cntR[y] = (int)__popcll(balR); }
}

// ---------------- K3: redundant scan + per-row sampling + output ------------
__device__ __forceinline__ int computePos(int i, int N) {
    if (N >= SS) {
        float t = ((float)i * (float)(N - 1)) / 1999.0f;  // float32 reference parity
        return (int)floorf(t);
    } else {
        return min(i, max(N - 1, 0));
    }
}

__global__ __launch_bounds__(256) void k_out(
        const float* __restrict__ depth, const u64* __restrict__ maskBits,
        const int* __restrict__ cntL, const int* __restrict__ cntR,
        const u16* __restrict__ xListL, const u16* __restrict__ xListR,
        float* __restrict__ out) {
#pragma clang fp contract(off)
    int y = blockIdx.x, t = threadIdx.x;
    __shared__ int sAcc[4];            // accLs, accLc, accRs, accRc
    __shared__ int sRow[6];            // cumLy, cLy, cumRy, cRy, Nl, Nr
    __shared__ float sInfo[4];         // slx, srx, sld, srd
    __shared__ int sValid;

    if (t == 0) { sAcc[0] = 0; sAcc[1] = 0; sAcc[2] = 0; sAcc[3] = 0; }

    u64 word = maskBits[(size_t)y * 32 + (t >> 3)];   // 8 threads share a word (broadcast)
    unsigned mbyte = (unsigned)((word >> ((t & 7) * 8)) & 0xFFull);
    const float4* drow = reinterpret_cast<const float4*>(depth + (size_t)y * W);
    float4 da = drow[2 * t], db = drow[2 * t + 1];
    int rowAny = __syncthreads_or(word != 0ull);      // also fences sAcc init

    // wave 0: redundant scan of row counts -> this row's cum/cnt + totals
    if (t < 64) {
        int base = t * 24;
        int sl = 0, sr = 0;
        for (int j = 0; j < 24; ++j) { sl += cntL[base + j]; sr += cntR[base + j]; }
        int iL = sl, iR = sr;
        for (int o = 1; o < 64; o <<= 1) {
            int vl = __shfl_up(iL, o, 64), vr = __shfl_up(iR, o, 64);
            if (t >= o) { iL += vl; iR += vr; }
        }
        int Nl = __shfl(iL, 63, 64), Nr = __shfl(iR, 63, 64);
        int c = y / 24;
        int cumLy = __shfl(iL - sl, c, 64);   // exclusive base of chunk c
        int cumRy = __shfl(iR - sr, c, 64);
        if (t == 0) {
            for (int j = c * 24; j < y; ++j) { cumLy += cntL[j]; cumRy += cntR[j]; }
            sRow[0] = cumLy; sRow[1] = cntL[y];
            sRow[2] = cumRy; sRow[3] = cntR[y];
            sRow[4] = Nl;    sRow[5] = Nr;
        }
    }
    __syncthreads();
    int cumLy = sRow[0], cLy = sRow[1], cumRy = sRow[2], cRy = sRow[3];
    int Nl = sRow[4], Nr = sRow[5];
    int vc = (Nl > 0 && Nr > 0) ? 1 : 0;

    // all threads: enumerate the 2000 samples, keep those landing in this row
    if (vc && (cLy | cRy)) {
        int aS = 0, aC = 0, bS = 0, bC = 0;
        for (int i = t; i < SS; i += 256) {
            int posL = computePos(i, Nl);
            int kL = posL - cumLy;
            if (kL >= 0 && kL < cLy) { aS += (int)xListL[(size_t)y * 64 + kL]; aC++; }
            int posR = computePos(i, Nr);
            int kR = posR - cumRy;
            if (kR >= 0 && kR < cRy) { bS += (int)xListR[(size_t)y * 64 + kR]; bC++; }
        }
        // wave reduce, lane 0 adds to LDS (integer: order-free)
        for (int o = 32; o > 0; o >>= 1) {
            aS += __shfl_down(aS, o, 64); aC += __shfl_down(aC, o, 64);
            bS += __shfl_down(bS, o, 64); bC += __shfl_down(bC, o, 64);
        }
        if ((t & 63) == 0) {
            if (aC) { atomicAdd(&sAcc[0], aS); atomicAdd(&sAcc[1], aC); }
            if (bC) { atomicAdd(&sAcc[2], bS); atomicAdd(&sAcc[3], bC); }
        }
    }
    __syncthreads();

    if (t == 0) {
        int lc = sAcc[1], rc = sAcc[3];
        float lmean = (float)sAcc[0] / fmaxf((float)lc, 1.0f);
        float rmean = (float)sAcc[2] / fmaxf((float)rc, 1.0f);
        int lx = min(max((int)rintf(lmean), 0), W - 1);
        int rx = min(max((int)rintf(rmean), 0), W - 1);
        float ld = depth[(size_t)y * W + lx], rd = depth[(size_t)y * W + rx];
        int valid = (lc > 0) && (rc > 0) && vc && (!isnan(ld)) && (!isnan(rd)) && rowAny;
        sInfo[0] = (float)lx; sInfo[1] = (float)rx; sInfo[2] = ld; sInfo[3] = rd;
        sValid = valid;
    }
    __syncthreads();

    float slx = sInfo[0], srx = sInfo[1], sld = sInfo[2], srd = sInfo[3];
    int valid = sValid;
    float denom = (srx - slx) + 1e-6f;

    float d8[8] = { da.x, da.y, da.z, da.w, db.x, db.y, db.z, db.w };
    float o8[8];
    int xb = t * 8;
#pragma unroll
    for (int j = 0; j < 8; ++j) {
        float o = d8[j];
        if (valid && ((mbyte >> j) & 1u)) {
            float r = ((float)(xb + j) - slx) / denom;
            r = fminf(fmaxf(r, 0.0f), 1.0f);
            o = (1.0f - r) * sld + r * srd;
        }
        o8[j] = o;
    }
    float4* orow = reinterpret_cast<float4*>(out + (size_t)y * W);
    orow[2 * t]     = make_float4(o8[0], o8[1], o8[2], o8[3]);
    orow[2 * t + 1] = make_float4(o8[4], o8[5], o8[6], o8[7]);
}

// ---------------- launcher ---------------------------------------------------
extern "C" void kernel_launch(void* const* d_in, const int* in_sizes, int n_in,
                              void* d_out, int out_size, void* d_ws, size_t ws_size,
                              hipStream_t stream) {
    const float* depth = (const float*)d_in[0];
    const int*   mask  = (const int*)d_in[1];
    const float* Kinv  = (const float*)d_in[2];
    float* out = (float*)d_out;
    char* ws = (char*)d_ws;

    u64* bitL = (u64*)(ws + OFF_BITL);
    u64* bitR = (u64*)(ws + OFF_BITR);
    u64* maskBits = (u64*)(ws + OFF_MBITS);
    float* partials = (float*)(ws + OFF_PART);
    int* cntL = (int*)(ws + OFF_CNTL);
    int* cntR = (int*)(ws + OFF_CNTR);
    float4* normBuf = (float4*)(ws + OFF_NORM);
    u16* xListL = (u16*)(ws + OFF_XL);
    u16* xListR = (u16*)(ws + OFF_XR);

    k_row_region<<<H, 256, 0, stream>>>(depth, mask, Kinv, bitL, bitR, maskBits, normBuf, partials);
    k_mean_inlier<<<H, 256, 0, stream>>>(partials, bitL, bitR, normBuf, xListL, xListR, cntL, cntR);
    k_out<<<H, 256, 0, stream>>>(depth, maskBits, cntL, cntR, xListL, xListR, out);
}